// Round 3
// baseline (208.569 us; speedup 1.0000x reference)
//
#include <hip/hip_runtime.h>

#define MAX_DISP 48

// Geometry fixed by reference: n=2, c=32, h=128, w=256
// out[n][c][d][h][x] = (x>=d) ? l[n][c][h][x] - r[n][c][h][x-d] : 1.0f
// out shape (n, c, MAX_DISP, h, w) float32 = 402.7 MB -> write-BW bound.

constexpr int W  = 256;
constexpr int H  = 128;
constexpr int D  = MAX_DISP;      // 48
constexpr int NC = 64;            // n*c
constexpr int NBLK = NC * D;      // 3072
constexpr int NXCD = 8;

// One block per (nc, d). Block writes the contiguous 128 KB slice
// out[nc][d][:][:]. XCD-swizzled so all 48 d-blocks of an nc share an XCD's
// L2 (2 MB of planes per XCD, fits 4 MB).
__global__ __launch_bounds__(256) void cost_volume_kernel(
    const float* __restrict__ l,
    const float* __restrict__ r,
    float* __restrict__ out)
{
    // XCD-aware chunked swizzle (bijective: NBLK % NXCD == 0).
    // Hardware assigns blockIdx.x round-robin to XCDs (bid % 8). Remap so
    // logical block g = consecutive chunk per XCD.
    const int bid = blockIdx.x;
    const int g   = (bid % NXCD) * (NBLK / NXCD) + bid / NXCD;

    const int d  = g % D;
    const int nc = g / D;

    const float* __restrict__ lp = l + (size_t)nc * H * W;
    const float* __restrict__ rp = r + (size_t)nc * H * W;
    float* __restrict__ op = out + (size_t)g * H * W;   // out[nc][d] slice

    const int t = threadIdx.x;

    // 32 iterations; unroll kept small so load live-ranges stay short
    // (full unroll spilled to scratch in a previous revision: 145us).
    #pragma unroll 4
    for (int k = 0; k < (H * W / 4) / 256; ++k) {
        const int flat = (t + k * 256) * 4;             // element index in slice
        const int x    = flat & (W - 1);                // column within row

        const float4 lv = *reinterpret_cast<const float4*>(lp + flat);

        // Shifted r reads: consecutive lanes -> consecutive addresses
        // (coalesced). Clamp covers flat<d (first row only); those
        // elements are masked to 1.0 anyway.
        const float r0 = rp[max(flat + 0 - d, 0)];
        const float r1 = rp[max(flat + 1 - d, 0)];
        const float r2 = rp[max(flat + 2 - d, 0)];
        const float r3 = rp[max(flat + 3 - d, 0)];

        float4 o;
        o.x = (x + 0 >= d) ? lv.x - r0 : 1.0f;
        o.y = (x + 1 >= d) ? lv.y - r1 : 1.0f;
        o.z = (x + 2 >= d) ? lv.z - r2 : 1.0f;
        o.w = (x + 3 >= d) ? lv.w - r3 : 1.0f;

        *reinterpret_cast<float4*>(op + flat) = o;
    }
}

extern "C" void kernel_launch(void* const* d_in, const int* in_sizes, int n_in,
                              void* d_out, int out_size, void* d_ws, size_t ws_size,
                              hipStream_t stream)
{
    const float* l = (const float*)d_in[0];
    const float* r = (const float*)d_in[1];
    float* out = (float*)d_out;

    cost_volume_kernel<<<NBLK, 256, 0, stream>>>(l, r, out);
}

// Round 5
// 69.257 us; speedup vs baseline: 3.0115x; 3.0115x over previous
//
#include <hip/hip_runtime.h>

#define MAX_DISP 48

// Geometry fixed by reference: n=2, c=32, h=128, w=256
// out[n][c][d][h][x] = (x>=d) ? l[n][c][h][x] - r[n][c][h][x-d] : 1.0f
// out shape (n, c, MAX_DISP, h, w) float32 = 402.7 MB -> write-BW bound.
//
// Structure (R0 lineage — fastest so far): one block per (n,c,h) row.
// r row staged in LDS once; l quad held in registers; each wave owns one
// d residue class (d = wave + 4k). Within a wave d is uniform, so the
// shifted r window slides by exactly 4 words per pass: ONE aligned,
// conflict-free ds_read_b128 per pass replaces R0's 4 stride-4 scalar
// reads (8-way bank conflict, ~43us/CU of LDS time).

constexpr int W  = 256;
constexpr int H  = 128;
constexpr int D  = MAX_DISP;   // 48
constexpr int HW = H * W;

// Native vector type for __builtin_nontemporal_store (HIP_vector_type is
// not accepted by the builtin).
typedef float vf4 __attribute__((ext_vector_type(4)));

template <int WAVE>
__device__ __forceinline__ void run_passes(const vf4* __restrict__ rs4,
                                           int lane, int xq, vf4 lv,
                                           float* __restrict__ obase)
{
    // Window at pass k covers r words [xq-4k-4, xq-4k+3]:
    //   wlo = rs[xq-4k-4 .. xq-4k-1], whi = rs[xq-4k .. xq-4k+3]
    // Needed value for output j: rs[xq+j-d], d = WAVE+4k -> window slot
    // 4 + j - WAVE (compile-time). Clamped (index<0) slots are only
    // selected when x<d, where the mask writes 1.0 anyway.
    vf4 wlo = rs4[max(lane - 1, 0)];
    vf4 whi = rs4[lane];

    #pragma unroll
    for (int k = 0; k < 12; ++k) {
        const int d = WAVE + 4 * k;

        float rv0, rv1, rv2, rv3;
        if constexpr (WAVE == 0) { rv0 = whi.x; rv1 = whi.y; rv2 = whi.z; rv3 = whi.w; }
        else if constexpr (WAVE == 1) { rv0 = wlo.w; rv1 = whi.x; rv2 = whi.y; rv3 = whi.z; }
        else if constexpr (WAVE == 2) { rv0 = wlo.z; rv1 = wlo.w; rv2 = whi.x; rv3 = whi.y; }
        else                          { rv0 = wlo.y; rv1 = wlo.z; rv2 = wlo.w; rv3 = whi.x; }

        vf4 o;
        o.x = (xq + 0 >= d) ? lv.x - rv0 : 1.0f;
        o.y = (xq + 1 >= d) ? lv.y - rv1 : 1.0f;
        o.z = (xq + 2 >= d) ? lv.z - rv2 : 1.0f;
        o.w = (xq + 3 >= d) ? lv.w - rv3 : 1.0f;

        __builtin_nontemporal_store(
            o, reinterpret_cast<vf4*>(obase + (size_t)d * HW + xq));

        if (k < 11) {                       // slide window down by 4 words
            whi = wlo;
            wlo = rs4[max(lane - k - 2, 0)];
        }
    }
}

__global__ __launch_bounds__(256) void cost_volume_kernel(
    const float* __restrict__ l,
    const float* __restrict__ r,
    float* __restrict__ out)
{
    const int row = blockIdx.x;           // nc*H + h, in [0, 8192)
    const int h   = row % H;
    const int nc  = row / H;

    __shared__ float rs[W];

    const int t    = threadIdx.x;
    const int wave = t >> 6;              // 0..3  (uniform within a wave)
    const int lane = t & 63;
    const int xq   = lane << 2;           // quad base column

    const float* __restrict__ lrow = l + (size_t)row * W;
    const float* __restrict__ rrow = r + (size_t)row * W;

    rs[t] = rrow[t];

    const vf4 lv = *reinterpret_cast<const vf4*>(lrow + xq);
    float* obase = out + (size_t)nc * D * HW + (size_t)h * W;

    __syncthreads();

    const vf4* rs4 = reinterpret_cast<const vf4*>(rs);
    switch (wave) {                       // wave-uniform branch
        case 0: run_passes<0>(rs4, lane, xq, lv, obase); break;
        case 1: run_passes<1>(rs4, lane, xq, lv, obase); break;
        case 2: run_passes<2>(rs4, lane, xq, lv, obase); break;
        default: run_passes<3>(rs4, lane, xq, lv, obase); break;
    }
}

extern "C" void kernel_launch(void* const* d_in, const int* in_sizes, int n_in,
                              void* d_out, int out_size, void* d_ws, size_t ws_size,
                              hipStream_t stream)
{
    const float* l = (const float*)d_in[0];
    const float* r = (const float*)d_in[1];
    float* out = (float*)d_out;

    const int nRows = 2 * 32 * H;         // 8192
    cost_volume_kernel<<<nRows, 256, 0, stream>>>(l, r, out);
}